// Round 14
// baseline (249.039 us; speedup 1.0000x reference)
//
#include <hip/hip_runtime.h>
#include <hip/hip_bf16.h>

#define TOKENS 512
#define IN_F 8192
#define OUT_F 8192
#define RANK 64
#define NNZ 8192

#define KSPLIT 4
#define KRANGE (IN_F / KSPLIT)   // 2048
#define BM 512
#define BN 64
#define BK 32
#define NT (KRANGE / BK)         // 64
#define LRSPLIT 16

typedef __attribute__((ext_vector_type(8))) short short8;
typedef __attribute__((ext_vector_type(4))) float f32x4;
typedef __attribute__((ext_vector_type(4))) int int4v;

__device__ __forceinline__ unsigned short f2bf(float f) {
  unsigned int u = __builtin_bit_cast(unsigned int, f);
  u += 0x7FFFu + ((u >> 16) & 1u);
  return (unsigned short)(u >> 16);
}
__device__ __forceinline__ float bf2f(unsigned short b) {
  unsigned int u = ((unsigned int)b) << 16;
  return __builtin_bit_cast(float, u);
}

__device__ __forceinline__ void gload_lds16(const void* g, void* l) {
  __builtin_amdgcn_global_load_lds(
      (const __attribute__((address_space(1))) unsigned int*)(g),
      (__attribute__((address_space(3))) unsigned int*)(l), 16, 0, 0);
}

#define WAIT_VM(n) asm volatile("s_waitcnt vmcnt(" #n ")" ::: "memory")

// K1: quantize x -> x_q; bf16 copy (lr1/outlier) and i8 copy (gemm)
__global__ __launch_bounds__(256) void k_quant(const float* __restrict__ x,
                                               const float* __restrict__ smooth,
                                               const float* __restrict__ act,
                                               unsigned short* __restrict__ Abf,
                                               unsigned char* __restrict__ Aq) {
  int idx = blockIdx.x * 256 + threadIdx.x;
  int base = idx * 4;
  int col = base & (IN_F - 1);
  float a = act[0];
  float4 xx = *(const float4*)(x + base);
  float4 ss = *(const float4*)(smooth + col);
  float q0 = fminf(fmaxf(rintf((xx.x / ss.x) / a), -128.f), 127.f);
  float q1 = fminf(fmaxf(rintf((xx.y / ss.y) / a), -128.f), 127.f);
  float q2 = fminf(fmaxf(rintf((xx.z / ss.z) / a), -128.f), 127.f);
  float q3 = fminf(fmaxf(rintf((xx.w / ss.w) / a), -128.f), 127.f);
  ushort4 o;
  o.x = f2bf(q0); o.y = f2bf(q1); o.z = f2bf(q2); o.w = f2bf(q3);
  *(ushort4*)(Abf + base) = o;
  int i0 = (int)q0, i1 = (int)q1, i2 = (int)q2, i3 = (int)q3;
  unsigned int p = (i0 & 0xFF) | ((i1 & 0xFF) << 8) | ((i2 & 0xFF) << 16) |
                   ((unsigned)(i3 & 0xFF) << 24);
  *(unsigned int*)(Aq + base) = p;
}

// K2: t[s][512][64] = partial (x_dq @ V)*S*a, 64 blocks, non-atomic slices
__global__ __launch_bounds__(256) void k_lr1(const unsigned short* __restrict__ Abf,
                                             const float* __restrict__ V,
                                             const float* __restrict__ S,
                                             const float* __restrict__ act,
                                             float* __restrict__ t) {
  int bid = blockIdx.x;
  int mb = (bid & 3) * 128;
  int ksp = bid >> 2;              // 0..15
  int kb0 = ksp * 512;
  int tid = threadIdx.x, w = tid >> 6, l = tid & 63;
  int lr = l & 15, lg = l >> 4;
  f32x4 acc[2][4] = {};
  for (int ks = 0; ks < 16; ++ks) {
    int kb = kb0 + ks * 32;
    short8 af[2];
#pragma unroll
    for (int fi = 0; fi < 2; ++fi) {
      int row = mb + w * 32 + fi * 16 + lr;
      af[fi] = *(const short8*)(Abf + (size_t)row * IN_F + kb + lg * 8);
    }
    short8 bfr[4];
#pragma unroll
    for (int fj = 0; fj < 4; ++fj) {
      int rk = fj * 16 + lr;
      short8 bv;
#pragma unroll
      for (int j = 0; j < 8; ++j)
        bv[j] = (short)f2bf(V[(size_t)(kb + lg * 8 + j) * RANK + rk]);
      bfr[fj] = bv;
    }
#pragma unroll
    for (int fi = 0; fi < 2; ++fi)
#pragma unroll
      for (int fj = 0; fj < 4; ++fj)
        acc[fi][fj] = __builtin_amdgcn_mfma_f32_16x16x32_bf16(af[fi], bfr[fj], acc[fi][fj], 0, 0, 0);
  }
  float a = act[0];
  float* tk = t + (size_t)ksp * TOKENS * RANK;
#pragma unroll
  for (int fi = 0; fi < 2; ++fi)
#pragma unroll
    for (int fj = 0; fj < 4; ++fj) {
      int rk = fj * 16 + lr;
      float sc = a * S[rk];
#pragma unroll
      for (int r = 0; r < 4; ++r) {
        int tok = mb + w * 32 + fi * 16 + lg * 4 + r;
        tk[(size_t)tok * RANK + rk] = acc[fi][fj][r] * sc;
      }
    }
}

// K3: out = bias + (Σ_s t[s]) @ U^T   (first writer of out)
__global__ __launch_bounds__(256) void k_lr2(const float* __restrict__ t,
                                             const float* __restrict__ U,
                                             const float* __restrict__ bias,
                                             float* __restrict__ out) {
  int bid = blockIdx.x;
  int mb = (bid & 3) * 128;
  int nb = (bid >> 2) * 128;
  int tid = threadIdx.x, w = tid >> 6, l = tid & 63;
  int lr = l & 15, lg = l >> 4;
  int wm = w >> 1, wn = w & 1;
  f32x4 acc[4][4] = {};
#pragma unroll
  for (int kk = 0; kk < 2; ++kk) {
    short8 af[4], bfr[4];
#pragma unroll
    for (int fi = 0; fi < 4; ++fi) {
      int row = mb + wm * 64 + fi * 16 + lr;
      size_t off = (size_t)row * RANK + kk * 32 + lg * 8;
      float4 t0 = {0, 0, 0, 0}, t1 = {0, 0, 0, 0};
      for (int s = 0; s < LRSPLIT; ++s) {
        const float4* tp = (const float4*)(t + (size_t)s * TOKENS * RANK + off);
        float4 u0 = tp[0], u1 = tp[1];
        t0.x += u0.x; t0.y += u0.y; t0.z += u0.z; t0.w += u0.w;
        t1.x += u1.x; t1.y += u1.y; t1.z += u1.z; t1.w += u1.w;
      }
      af[fi][0] = f2bf(t0.x); af[fi][1] = f2bf(t0.y);
      af[fi][2] = f2bf(t0.z); af[fi][3] = f2bf(t0.w);
      af[fi][4] = f2bf(t1.x); af[fi][5] = f2bf(t1.y);
      af[fi][6] = f2bf(t1.z); af[fi][7] = f2bf(t1.w);
    }
#pragma unroll
    for (int fj = 0; fj < 4; ++fj) {
      int row = nb + wn * 64 + fj * 16 + lr;
      const float4* up = (const float4*)(U + (size_t)row * RANK + kk * 32 + lg * 8);
      float4 u0 = up[0], u1 = up[1];
      bfr[fj][0] = f2bf(u0.x); bfr[fj][1] = f2bf(u0.y);
      bfr[fj][2] = f2bf(u0.z); bfr[fj][3] = f2bf(u0.w);
      bfr[fj][4] = f2bf(u1.x); bfr[fj][5] = f2bf(u1.y);
      bfr[fj][6] = f2bf(u1.z); bfr[fj][7] = f2bf(u1.w);
    }
#pragma unroll
    for (int fi = 0; fi < 4; ++fi)
#pragma unroll
      for (int fj = 0; fj < 4; ++fj)
        acc[fi][fj] = __builtin_amdgcn_mfma_f32_16x16x32_bf16(af[fi], bfr[fj], acc[fi][fj], 0, 0, 0);
  }
#pragma unroll
  for (int fj = 0; fj < 4; ++fj) {
    int o = nb + wn * 64 + fj * 16 + lr;
    float b = bias[o];
#pragma unroll
    for (int fi = 0; fi < 4; ++fi)
#pragma unroll
      for (int r = 0; r < 4; ++r) {
        int tok = mb + wm * 64 + fi * 16 + lg * 4 + r;
        out[(size_t)tok * OUT_F + o] = b + acc[fi][fj][r];
      }
  }
}

// K4: outliers + merge of 4 int32 GEMM partial slices
__global__ __launch_bounds__(256) void k_outlier_merge(
    const unsigned short* __restrict__ Abf, const int* __restrict__ rows,
    const int* __restrict__ cols, const float* __restrict__ vals,
    const float* __restrict__ act, const float* __restrict__ wscale,
    const int* __restrict__ part, float* __restrict__ out) {
  __shared__ float accr[OUT_F];
  int tk = blockIdx.x;
  for (int i = threadIdx.x; i < OUT_F; i += 256) accr[i] = 0.f;
  __syncthreads();
  float a = act[0];
  for (int i = threadIdx.x; i < NNZ; i += 256) {
    int r = rows[i], c = cols[i];
    float v = vals[i];
    float xq = bf2f(Abf[(size_t)tk * IN_F + c]);
    atomicAdd(accr + r, a * xq * v);
  }
  __syncthreads();
  float* orow = out + (size_t)tk * OUT_F;
  const int* p0 = part + (size_t)tk * OUT_F;
  const int* p1 = p0 + (size_t)TOKENS * OUT_F;
  const int* p2 = p1 + (size_t)TOKENS * OUT_F;
  const int* p3 = p2 + (size_t)TOKENS * OUT_F;
  for (int i = threadIdx.x * 4; i < OUT_F; i += 1024) {
    int4v s0 = *(const int4v*)(p0 + i);
    int4v s1 = *(const int4v*)(p1 + i);
    int4v s2 = *(const int4v*)(p2 + i);
    int4v s3 = *(const int4v*)(p3 + i);
    float4 ws = *(const float4*)(wscale + i);
    float4 ov = *(const float4*)(orow + i);
    ov.x += accr[i + 0] + (float)(s0[0] + s1[0] + s2[0] + s3[0]) * a * ws.x;
    ov.y += accr[i + 1] + (float)(s0[1] + s1[1] + s2[1] + s3[1]) * a * ws.y;
    ov.z += accr[i + 2] + (float)(s0[2] + s1[2] + s2[2] + s3[2]) * a * ws.z;
    ov.w += accr[i + 3] + (float)(s0[3] + s1[3] + s2[3] + s3[3]) * a * ws.w;
    *(float4*)(orow + i) = ov;
  }
}

// K5: part[ks] = x_q @ Wq[:,slice]^T — m97-regime replica:
// 4-wave blocks (256 thr), BK=32, plain __syncthreads dbuf, ~164 VGPR ->
// 3 resident blocks/CU (the measured 23 B/cyc/CU point). BM=512 (W read
// once), BN=64, KSPLIT=4, mfma_i32_16x16x32_i8, i32 partial stores.
__global__ __launch_bounds__(256, 3) void k_gemm(const unsigned char* __restrict__ Aq,
                                                 const int* __restrict__ W,
                                                 int* __restrict__ part) {
  __shared__ __align__(16) unsigned char As[2][BM * BK];  // 32 KB
  __shared__ __align__(16) unsigned char Bs[2][BN * BK];  // 4 KB

  // XCD pair {2k,2k+1} owns ks=k (A-slice 1MB L2-resident per XCD pair)
  int d = blockIdx.x;
  int wg = (d & 7) * 64 + (d >> 3);   // 0..511
  int ks = wg >> 7;                   // 0..3
  int nb = wg & 127;                  // 0..127
  int kb0 = ks * KRANGE;

  int tid = threadIdx.x, w = tid >> 6, l = tid & 63;
  int lr = l & 15, lg = l >> 4;       // 4 waves, all-M; wave tile 128x64

  int4v acc[8][4] = {};
  int4v wr[2];

  const int rW = tid >> 2;            // W row 0..63
  const int kcW = (tid & 3) * 8;      // int32 offset within BK (8 int32)
  const int uW = (kcW >> 4) ^ ((rW >> 1) & 1);
  const int hW = (kcW >> 3) & 1;

  auto LOAD_W = [&](int kt) {
    const int* wp = W + (size_t)(nb * BN + rW) * IN_F + kb0 + kt * BK + kcW;
    wr[0] = *(const int4v*)wp;
    wr[1] = *(const int4v*)(wp + 4);
  };
  // A i8 -> LDS direct; 4 x gload_lds16/thread; linear dest, pre-swizzled src
  auto STAGE_A = [&](int buf, int kt) {
    int kb = kb0 + kt * BK;
#pragma unroll
    for (int i = 0; i < 4; ++i) {
      int base = i * 256 + w * 64;     // wave-uniform 16B-unit base
      int idx = base + l;
      int r = idx >> 1, u = idx & 1;
      int us = u ^ ((r >> 1) & 1);
      gload_lds16(Aq + (size_t)r * IN_F + kb + us * 16,
                  &As[buf][(size_t)base * 16]);
    }
  };
  auto WRITE_B = [&](int buf) {
    unsigned int w0 = 0, w1 = 0;
#pragma unroll
    for (int j = 0; j < 4; ++j) w0 |= ((unsigned)(wr[0][j] & 0xFF)) << (8 * j);
#pragma unroll
    for (int j = 0; j < 4; ++j) w1 |= ((unsigned)(wr[1][j] & 0xFF)) << (8 * j);
    uint2 val; val.x = w0; val.y = w1;
    *(uint2*)(&Bs[buf][(size_t)rW * BK + uW * 16 + hW * 8]) = val;
  };
  auto LDFA = [&](int buf, int row) -> long {
    int u = (lg >> 1) ^ ((row >> 1) & 1);
    return *(const long*)(&As[buf][(size_t)row * BK + u * 16 + (lg & 1) * 8]);
  };
  auto LDFB = [&](int buf, int row) -> long {
    int u = (lg >> 1) ^ ((row >> 1) & 1);
    return *(const long*)(&Bs[buf][(size_t)row * BK + u * 16 + (lg & 1) * 8]);
  };
  auto COMPUTE = [&](int buf) {
    long bfrag[4];
#pragma unroll
    for (int fj = 0; fj < 4; ++fj) bfrag[fj] = LDFB(buf, fj * 16 + lr);
    __builtin_amdgcn_s_setprio(1);
#pragma unroll
    for (int fi = 0; fi < 8; ++fi) {
      long af = LDFA(buf, w * 128 + fi * 16 + lr);
#pragma unroll
      for (int fj = 0; fj < 4; ++fj)
        acc[fi][fj] = __builtin_amdgcn_mfma_i32_16x16x32_i8(af, bfrag[fj],
                                                            acc[fi][fj], 0, 0, 0);
    }
    __builtin_amdgcn_s_setprio(0);
  };

  // prologue
  LOAD_W(0);
  STAGE_A(0, 0);
  WAIT_VM(4);       // retire the 2 W loads (oldest); A gloads stay pending
  WRITE_B(0);
  __syncthreads();  // compiler drains vmcnt/lgkmcnt here (m97 pattern)

  for (int kt = 0; kt < NT; ++kt) {
    int cur = kt & 1;
    if (kt + 1 < NT) {
      LOAD_W(kt + 1);
      STAGE_A(cur ^ 1, kt + 1);
    }
    COMPUTE(cur);
    if (kt + 1 < NT) {
      WAIT_VM(4);   // retire next-tile W loads for the pack
      WRITE_B(cur ^ 1);
    }
    __syncthreads();
  }

  // streaming i32 partial stores (unique writer per slice)
  int* pp = part + (size_t)ks * TOKENS * OUT_F;
#pragma unroll
  for (int fj = 0; fj < 4; ++fj) {
    int o = nb * BN + fj * 16 + lr;
#pragma unroll
    for (int fi = 0; fi < 8; ++fi)
#pragma unroll
      for (int rr = 0; rr < 4; ++rr) {
        int tok = w * 128 + fi * 16 + lg * 4 + rr;
        pp[(size_t)tok * OUT_F + o] = acc[fi][fj][rr];
      }
  }
}

extern "C" void kernel_launch(void* const* d_in, const int* in_sizes, int n_in,
                              void* d_out, int out_size, void* d_ws, size_t ws_size,
                              hipStream_t stream) {
  const float* x = (const float*)d_in[0];
  const int* W = (const int*)d_in[1];
  const float* wscale = (const float*)d_in[2];
  const float* smooth = (const float*)d_in[3];
  const float* act = (const float*)d_in[4];
  const int* orow = (const int*)d_in[5];
  const int* ocol = (const int*)d_in[6];
  const float* oval = (const float*)d_in[7];
  const float* U = (const float*)d_in[8];
  const float* S = (const float*)d_in[9];
  const float* V = (const float*)d_in[10];
  const float* bias = (const float*)d_in[11];
  float* out = (float*)d_out;

  unsigned short* Abf = (unsigned short*)d_ws;                           // 8 MB
  unsigned char* Aq = (unsigned char*)d_ws + (size_t)TOKENS * IN_F * 2;  // 4 MB
  float* t = (float*)((char*)d_ws + (size_t)TOKENS * IN_F * 3);          // 2 MB
  int* part = (int*)((char*)d_ws + (size_t)TOKENS * IN_F * 3 +
                     (size_t)LRSPLIT * TOKENS * RANK * 4);               // 64 MB

  k_quant<<<(TOKENS * IN_F / 4) / 256, 256, 0, stream>>>(x, smooth, act, Abf, Aq);
  k_gemm<<<512, 256, 0, stream>>>(Aq, W, part);
  k_lr1<<<64, 256, 0, stream>>>(Abf, V, S, act, t);
  k_lr2<<<256, 256, 0, stream>>>(t, U, bias, out);
  k_outlier_merge<<<TOKENS, 256, 0, stream>>>(Abf, orow, ocol, oval, act,
                                              wscale, part, out);
}

// Round 15
// 230.536 us; speedup vs baseline: 1.0803x; 1.0803x over previous
//
#include <hip/hip_runtime.h>
#include <hip/hip_bf16.h>

#define TOKENS 512
#define IN_F 8192
#define OUT_F 8192
#define RANK 64
#define NNZ 8192

#define KSPLIT 4
#define KRANGE (IN_F / KSPLIT)   // 2048
#define BM 256
#define BN 128
#define BK 64
#define NT (KRANGE / BK)         // 32
#define LRSPLIT 16

typedef __attribute__((ext_vector_type(8))) short short8;
typedef __attribute__((ext_vector_type(4))) float f32x4;
typedef __attribute__((ext_vector_type(4))) int int4v;

__device__ __forceinline__ unsigned short f2bf(float f) {
  unsigned int u = __builtin_bit_cast(unsigned int, f);
  u += 0x7FFFu + ((u >> 16) & 1u);
  return (unsigned short)(u >> 16);
}
__device__ __forceinline__ float bf2f(unsigned short b) {
  unsigned int u = ((unsigned int)b) << 16;
  return __builtin_bit_cast(float, u);
}

__device__ __forceinline__ void gload_lds16(const void* g, void* l) {
  __builtin_amdgcn_global_load_lds(
      (const __attribute__((address_space(1))) unsigned int*)(g),
      (__attribute__((address_space(3))) unsigned int*)(l), 16, 0, 0);
}

// K0: pre-pack W int32 -> i8 (low byte IS the value for [-128,127])
__global__ __launch_bounds__(256) void k_prep(const int* __restrict__ W,
                                              unsigned char* __restrict__ Wq8) {
  size_t idx = ((size_t)blockIdx.x * 256 + threadIdx.x) * 4;
  int4v v = *(const int4v*)(W + idx);
  uchar4 p;
  p.x = (unsigned char)(v[0] & 0xFF);
  p.y = (unsigned char)(v[1] & 0xFF);
  p.z = (unsigned char)(v[2] & 0xFF);
  p.w = (unsigned char)(v[3] & 0xFF);
  *(uchar4*)(Wq8 + idx) = p;
}

// K1: quantize x -> x_q; bf16 copy (lr1/outlier) and i8 copy (gemm)
__global__ __launch_bounds__(256) void k_quant(const float* __restrict__ x,
                                               const float* __restrict__ smooth,
                                               const float* __restrict__ act,
                                               unsigned short* __restrict__ Abf,
                                               unsigned char* __restrict__ Aq) {
  int idx = blockIdx.x * 256 + threadIdx.x;
  int base = idx * 4;
  int col = base & (IN_F - 1);
  float a = act[0];
  float4 xx = *(const float4*)(x + base);
  float4 ss = *(const float4*)(smooth + col);
  float q0 = fminf(fmaxf(rintf((xx.x / ss.x) / a), -128.f), 127.f);
  float q1 = fminf(fmaxf(rintf((xx.y / ss.y) / a), -128.f), 127.f);
  float q2 = fminf(fmaxf(rintf((xx.z / ss.z) / a), -128.f), 127.f);
  float q3 = fminf(fmaxf(rintf((xx.w / ss.w) / a), -128.f), 127.f);
  ushort4 o;
  o.x = f2bf(q0); o.y = f2bf(q1); o.z = f2bf(q2); o.w = f2bf(q3);
  *(ushort4*)(Abf + base) = o;
  int i0 = (int)q0, i1 = (int)q1, i2 = (int)q2, i3 = (int)q3;
  unsigned int p = (i0 & 0xFF) | ((i1 & 0xFF) << 8) | ((i2 & 0xFF) << 16) |
                   ((unsigned)(i3 & 0xFF) << 24);
  *(unsigned int*)(Aq + base) = p;
}

// K2: t[s][512][64] = partial (x_dq @ V)*S*a, 64 blocks, non-atomic slices
__global__ __launch_bounds__(256) void k_lr1(const unsigned short* __restrict__ Abf,
                                             const float* __restrict__ V,
                                             const float* __restrict__ S,
                                             const float* __restrict__ act,
                                             float* __restrict__ t) {
  int bid = blockIdx.x;
  int mb = (bid & 3) * 128;
  int ksp = bid >> 2;              // 0..15
  int kb0 = ksp * 512;
  int tid = threadIdx.x, w = tid >> 6, l = tid & 63;
  int lr = l & 15, lg = l >> 4;
  f32x4 acc[2][4] = {};
  for (int ks = 0; ks < 16; ++ks) {
    int kb = kb0 + ks * 32;
    short8 af[2];
#pragma unroll
    for (int fi = 0; fi < 2; ++fi) {
      int row = mb + w * 32 + fi * 16 + lr;
      af[fi] = *(const short8*)(Abf + (size_t)row * IN_F + kb + lg * 8);
    }
    short8 bfr[4];
#pragma unroll
    for (int fj = 0; fj < 4; ++fj) {
      int rk = fj * 16 + lr;
      short8 bv;
#pragma unroll
      for (int j = 0; j < 8; ++j)
        bv[j] = (short)f2bf(V[(size_t)(kb + lg * 8 + j) * RANK + rk]);
      bfr[fj] = bv;
    }
#pragma unroll
    for (int fi = 0; fi < 2; ++fi)
#pragma unroll
      for (int fj = 0; fj < 4; ++fj)
        acc[fi][fj] = __builtin_amdgcn_mfma_f32_16x16x32_bf16(af[fi], bfr[fj], acc[fi][fj], 0, 0, 0);
  }
  float a = act[0];
  float* tk = t + (size_t)ksp * TOKENS * RANK;
#pragma unroll
  for (int fi = 0; fi < 2; ++fi)
#pragma unroll
    for (int fj = 0; fj < 4; ++fj) {
      int rk = fj * 16 + lr;
      float sc = a * S[rk];
#pragma unroll
      for (int r = 0; r < 4; ++r) {
        int tok = mb + w * 32 + fi * 16 + lg * 4 + r;
        tk[(size_t)tok * RANK + rk] = acc[fi][fj][r] * sc;
      }
    }
}

// K3: out = bias + (Σ_s t[s]) @ U^T   (first writer of out)
__global__ __launch_bounds__(256) void k_lr2(const float* __restrict__ t,
                                             const float* __restrict__ U,
                                             const float* __restrict__ bias,
                                             float* __restrict__ out) {
  int bid = blockIdx.x;
  int mb = (bid & 3) * 128;
  int nb = (bid >> 2) * 128;
  int tid = threadIdx.x, w = tid >> 6, l = tid & 63;
  int lr = l & 15, lg = l >> 4;
  int wm = w >> 1, wn = w & 1;
  f32x4 acc[4][4] = {};
#pragma unroll
  for (int kk = 0; kk < 2; ++kk) {
    short8 af[4], bfr[4];
#pragma unroll
    for (int fi = 0; fi < 4; ++fi) {
      int row = mb + wm * 64 + fi * 16 + lr;
      size_t off = (size_t)row * RANK + kk * 32 + lg * 8;
      float4 t0 = {0, 0, 0, 0}, t1 = {0, 0, 0, 0};
      for (int s = 0; s < LRSPLIT; ++s) {
        const float4* tp = (const float4*)(t + (size_t)s * TOKENS * RANK + off);
        float4 u0 = tp[0], u1 = tp[1];
        t0.x += u0.x; t0.y += u0.y; t0.z += u0.z; t0.w += u0.w;
        t1.x += u1.x; t1.y += u1.y; t1.z += u1.z; t1.w += u1.w;
      }
      af[fi][0] = f2bf(t0.x); af[fi][1] = f2bf(t0.y);
      af[fi][2] = f2bf(t0.z); af[fi][3] = f2bf(t0.w);
      af[fi][4] = f2bf(t1.x); af[fi][5] = f2bf(t1.y);
      af[fi][6] = f2bf(t1.z); af[fi][7] = f2bf(t1.w);
    }
#pragma unroll
    for (int fj = 0; fj < 4; ++fj) {
      int row = nb + wn * 64 + fj * 16 + lr;
      const float4* up = (const float4*)(U + (size_t)row * RANK + kk * 32 + lg * 8);
      float4 u0 = up[0], u1 = up[1];
      bfr[fj][0] = f2bf(u0.x); bfr[fj][1] = f2bf(u0.y);
      bfr[fj][2] = f2bf(u0.z); bfr[fj][3] = f2bf(u0.w);
      bfr[fj][4] = f2bf(u1.x); bfr[fj][5] = f2bf(u1.y);
      bfr[fj][6] = f2bf(u1.z); bfr[fj][7] = f2bf(u1.w);
    }
#pragma unroll
    for (int fi = 0; fi < 4; ++fi)
#pragma unroll
      for (int fj = 0; fj < 4; ++fj)
        acc[fi][fj] = __builtin_amdgcn_mfma_f32_16x16x32_bf16(af[fi], bfr[fj], acc[fi][fj], 0, 0, 0);
  }
#pragma unroll
  for (int fj = 0; fj < 4; ++fj) {
    int o = nb + wn * 64 + fj * 16 + lr;
    float b = bias[o];
#pragma unroll
    for (int fi = 0; fi < 4; ++fi)
#pragma unroll
      for (int r = 0; r < 4; ++r) {
        int tok = mb + wm * 64 + fi * 16 + lg * 4 + r;
        out[(size_t)tok * OUT_F + o] = b + acc[fi][fj][r];
      }
  }
}

// K4: outliers + merge of 4 int32 GEMM partial slices
__global__ __launch_bounds__(256) void k_outlier_merge(
    const unsigned short* __restrict__ Abf, const int* __restrict__ rows,
    const int* __restrict__ cols, const float* __restrict__ vals,
    const float* __restrict__ act, const float* __restrict__ wscale,
    const int* __restrict__ part, float* __restrict__ out) {
  __shared__ float accr[OUT_F];
  int tk = blockIdx.x;
  for (int i = threadIdx.x; i < OUT_F; i += 256) accr[i] = 0.f;
  __syncthreads();
  float a = act[0];
  for (int i = threadIdx.x; i < NNZ; i += 256) {
    int r = rows[i], c = cols[i];
    float v = vals[i];
    float xq = bf2f(Abf[(size_t)tk * IN_F + c]);
    atomicAdd(accr + r, a * xq * v);
  }
  __syncthreads();
  float* orow = out + (size_t)tk * OUT_F;
  const int* p0 = part + (size_t)tk * OUT_F;
  const int* p1 = p0 + (size_t)TOKENS * OUT_F;
  const int* p2 = p1 + (size_t)TOKENS * OUT_F;
  const int* p3 = p2 + (size_t)TOKENS * OUT_F;
  for (int i = threadIdx.x * 4; i < OUT_F; i += 1024) {
    int4v s0 = *(const int4v*)(p0 + i);
    int4v s1 = *(const int4v*)(p1 + i);
    int4v s2 = *(const int4v*)(p2 + i);
    int4v s3 = *(const int4v*)(p3 + i);
    float4 ws = *(const float4*)(wscale + i);
    float4 ov = *(const float4*)(orow + i);
    ov.x += accr[i + 0] + (float)(s0[0] + s1[0] + s2[0] + s3[0]) * a * ws.x;
    ov.y += accr[i + 1] + (float)(s0[1] + s1[1] + s2[1] + s3[1]) * a * ws.y;
    ov.z += accr[i + 2] + (float)(s0[2] + s1[2] + s2[2] + s3[2]) * a * ws.z;
    ov.w += accr[i + 3] + (float)(s0[3] + s1[3] + s2[3] + s3[3]) * a * ws.w;
    *(float4*)(orow + i) = ov;
  }
}

// K5: m97-clone GEMM — BOTH operands i8 staged via global_load_lds (no
// reg-staging, no ds_write, no vmcnt asm). BM=256, BN=128, BK=64, KSPLIT=4,
// 256 thr (4 waves), 48 KB LDS dbuf, ~164 VGPR -> 3 blocks/CU (12 waves).
// One __syncthreads per K-step; drain covered by co-resident blocks (m114).
__global__ __launch_bounds__(256, 3) void k_gemm(const unsigned char* __restrict__ Aq,
                                                 const unsigned char* __restrict__ Wq8,
                                                 int* __restrict__ part) {
  __shared__ __align__(16) unsigned char As[2][BM * BK];  // 32 KB
  __shared__ __align__(16) unsigned char Bs[2][BN * BK];  // 16 KB

  // XCD x owns (ks = x>>1, mb = x&1): A-slice 512KB L2-resident per XCD
  int d = blockIdx.x;
  int wg = (d & 7) * 64 + (d >> 3);   // 0..511
  int ks = wg >> 7;                   // 0..3
  int mb = (wg >> 6) & 1;             // 0..1
  int nb = wg & 63;                   // 0..63
  int kb0 = ks * KRANGE;

  int tid = threadIdx.x, w = tid >> 6, l = tid & 63;
  int lr = l & 15, lg = l >> 4;
  int wm = w >> 1, wn = w & 1;        // wave tile 128x64

  int4v acc[8][4] = {};

  // A i8 -> LDS; linear dest, pre-swizzled source (u ^= (row>>1)&3)
  auto STAGE = [&](int buf, int kt) {
    int kb = kb0 + kt * BK;
#pragma unroll
    for (int i = 0; i < 4; ++i) {       // A: 256x64 = 16KB = 4 issues
      int base = i * 256 + w * 64;
      int unit = base + l;
      int r = unit >> 2, up = unit & 3;
      int u = up ^ ((r >> 1) & 3);
      gload_lds16(Aq + (size_t)(mb * BM + r) * IN_F + kb + u * 16,
                  &As[buf][(size_t)base * 16]);
    }
#pragma unroll
    for (int i = 0; i < 2; ++i) {       // B: 128x64 = 8KB = 2 issues
      int base = i * 256 + w * 64;
      int unit = base + l;
      int r = unit >> 2, up = unit & 3;
      int u = up ^ ((r >> 1) & 3);
      gload_lds16(Wq8 + (size_t)(nb * BN + r) * IN_F + kb + u * 16,
                  &Bs[buf][(size_t)base * 16]);
    }
  };
  auto LDFA = [&](int buf, int row) -> int4v {
    int u = lg ^ ((row >> 1) & 3);
    return *(const int4v*)(&As[buf][(size_t)row * BK + u * 16]);
  };
  auto LDFB = [&](int buf, int row) -> int4v {
    int u = lg ^ ((row >> 1) & 3);
    return *(const int4v*)(&Bs[buf][(size_t)row * BK + u * 16]);
  };
  auto COMPUTE = [&](int buf) {
    int4v b0 = LDFB(buf, wn * 64 + 0 * 16 + lr);
    int4v b1 = LDFB(buf, wn * 64 + 1 * 16 + lr);
    int4v b2 = LDFB(buf, wn * 64 + 2 * 16 + lr);
    int4v b3 = LDFB(buf, wn * 64 + 3 * 16 + lr);
    __builtin_amdgcn_s_setprio(1);
#pragma unroll
    for (int fi = 0; fi < 8; ++fi) {
      int4v af = LDFA(buf, wm * 128 + fi * 16 + lr);
      acc[fi][0] = __builtin_amdgcn_mfma_i32_16x16x64_i8(af, b0, acc[fi][0], 0, 0, 0);
      acc[fi][1] = __builtin_amdgcn_mfma_i32_16x16x64_i8(af, b1, acc[fi][1], 0, 0, 0);
      acc[fi][2] = __builtin_amdgcn_mfma_i32_16x16x64_i8(af, b2, acc[fi][2], 0, 0, 0);
      acc[fi][3] = __builtin_amdgcn_mfma_i32_16x16x64_i8(af, b3, acc[fi][3], 0, 0, 0);
    }
    __builtin_amdgcn_s_setprio(0);
  };

  STAGE(0, 0);
  __syncthreads();

  for (int kt = 0; kt < NT; ++kt) {
    int cur = kt & 1;
    if (kt + 1 < NT) STAGE(cur ^ 1, kt + 1);
    COMPUTE(cur);
    __syncthreads();
  }

  // streaming i32 partial stores (unique writer per slice)
  int* pp = part + (size_t)ks * TOKENS * OUT_F;
#pragma unroll
  for (int fj = 0; fj < 4; ++fj) {
    int o = nb * BN + wn * 64 + fj * 16 + lr;
#pragma unroll
    for (int fi = 0; fi < 8; ++fi)
#pragma unroll
      for (int rr = 0; rr < 4; ++rr) {
        int tok = mb * BM + wm * 128 + fi * 16 + lg * 4 + rr;
        pp[(size_t)tok * OUT_F + o] = acc[fi][fj][rr];
      }
  }
}

extern "C" void kernel_launch(void* const* d_in, const int* in_sizes, int n_in,
                              void* d_out, int out_size, void* d_ws, size_t ws_size,
                              hipStream_t stream) {
  const float* x = (const float*)d_in[0];
  const int* W = (const int*)d_in[1];
  const float* wscale = (const float*)d_in[2];
  const float* smooth = (const float*)d_in[3];
  const float* act = (const float*)d_in[4];
  const int* orow = (const int*)d_in[5];
  const int* ocol = (const int*)d_in[6];
  const float* oval = (const float*)d_in[7];
  const float* U = (const float*)d_in[8];
  const float* S = (const float*)d_in[9];
  const float* V = (const float*)d_in[10];
  const float* bias = (const float*)d_in[11];
  float* out = (float*)d_out;

  unsigned short* Abf = (unsigned short*)d_ws;                           // 8 MB
  unsigned char* Aq = (unsigned char*)d_ws + (size_t)TOKENS * IN_F * 2;  // 4 MB
  float* t = (float*)((char*)d_ws + (size_t)TOKENS * IN_F * 3);          // 2 MB
  int* part = (int*)((char*)d_ws + (size_t)TOKENS * IN_F * 3 +
                     (size_t)LRSPLIT * TOKENS * RANK * 4);               // 64 MB
  unsigned char* Wq8 = (unsigned char*)part + (size_t)KSPLIT * TOKENS * OUT_F * 4;  // 64 MB

  k_prep<<<(size_t)OUT_F * IN_F / 4 / 256, 256, 0, stream>>>(W, Wq8);
  k_quant<<<(TOKENS * IN_F / 4) / 256, 256, 0, stream>>>(x, smooth, act, Abf, Aq);
  k_gemm<<<512, 256, 0, stream>>>(Aq, Wq8, part);
  k_lr1<<<64, 256, 0, stream>>>(Abf, V, S, act, t);
  k_lr2<<<256, 256, 0, stream>>>(t, U, bias, out);
  k_outlier_merge<<<TOKENS, 256, 0, stream>>>(Abf, orow, ocol, oval, act,
                                              wscale, part, out);
}

// Round 16
// 184.922 us; speedup vs baseline: 1.3467x; 1.2467x over previous
//
#include <hip/hip_runtime.h>
#include <hip/hip_bf16.h>

#define TOKENS 512
#define IN_F 8192
#define OUT_F 8192
#define RANK 64
#define NNZ 8192

#define KSPLIT 4
#define KRANGE (IN_F / KSPLIT)   // 2048
#define BM 512
#define BN 128
#define BK 64
#define NT (KRANGE / BK)         // 32

typedef __attribute__((ext_vector_type(8))) short short8;
typedef __attribute__((ext_vector_type(4))) float f32x4;
typedef __attribute__((ext_vector_type(4))) int int4v;

__device__ __forceinline__ unsigned short f2bf(float f) {
  unsigned int u = __builtin_bit_cast(unsigned int, f);
  u += 0x7FFFu + ((u >> 16) & 1u);
  return (unsigned short)(u >> 16);
}
__device__ __forceinline__ float bf2f(unsigned short b) {
  unsigned int u = ((unsigned int)b) << 16;
  return __builtin_bit_cast(float, u);
}

__device__ __forceinline__ void gload_lds16(const void* g, void* l) {
  __builtin_amdgcn_global_load_lds(
      (const __attribute__((address_space(1))) unsigned int*)(g),
      (__attribute__((address_space(3))) unsigned int*)(l), 16, 0, 0);
}

#define WAIT_VM(n) asm volatile("s_waitcnt vmcnt(" #n ")" ::: "memory")
#define WAIT_LGKM0 asm volatile("s_waitcnt lgkmcnt(0)" ::: "memory")
#define SCHED0 __builtin_amdgcn_sched_barrier(0)

// K1: quantize x -> x_q; bf16 copy (lr1/outlier) and i8 copy (gemm)
__global__ __launch_bounds__(256) void k_quant(const float* __restrict__ x,
                                               const float* __restrict__ smooth,
                                               const float* __restrict__ act,
                                               unsigned short* __restrict__ Abf,
                                               unsigned char* __restrict__ Aq) {
  int idx = blockIdx.x * 256 + threadIdx.x;
  int base = idx * 4;
  int col = base & (IN_F - 1);
  float a = act[0];
  float4 xx = *(const float4*)(x + base);
  float4 ss = *(const float4*)(smooth + col);
  float q0 = fminf(fmaxf(rintf((xx.x / ss.x) / a), -128.f), 127.f);
  float q1 = fminf(fmaxf(rintf((xx.y / ss.y) / a), -128.f), 127.f);
  float q2 = fminf(fmaxf(rintf((xx.z / ss.z) / a), -128.f), 127.f);
  float q3 = fminf(fmaxf(rintf((xx.w / ss.w) / a), -128.f), 127.f);
  ushort4 o;
  o.x = f2bf(q0); o.y = f2bf(q1); o.z = f2bf(q2); o.w = f2bf(q3);
  *(ushort4*)(Abf + base) = o;
  int i0 = (int)q0, i1 = (int)q1, i2 = (int)q2, i3 = (int)q3;
  unsigned int p = (i0 & 0xFF) | ((i1 & 0xFF) << 8) | ((i2 & 0xFF) << 16) |
                   ((unsigned)(i3 & 0xFF) << 24);
  *(unsigned int*)(Aq + base) = p;
}

// K2: t[512][64] = (x_dq @ V) * S*a   (64 blocks, atomic K-split accum)
__global__ __launch_bounds__(256) void k_lr1(const unsigned short* __restrict__ Abf,
                                             const float* __restrict__ V,
                                             const float* __restrict__ S,
                                             const float* __restrict__ act,
                                             float* __restrict__ t) {
  int bid = blockIdx.x;
  int mb = (bid & 3) * 128;
  int kb0 = (bid >> 2) * 512;
  int tid = threadIdx.x, w = tid >> 6, l = tid & 63;
  int lr = l & 15, lg = l >> 4;
  f32x4 acc[2][4] = {};
  for (int ks = 0; ks < 16; ++ks) {
    int kb = kb0 + ks * 32;
    short8 af[2];
#pragma unroll
    for (int fi = 0; fi < 2; ++fi) {
      int row = mb + w * 32 + fi * 16 + lr;
      af[fi] = *(const short8*)(Abf + (size_t)row * IN_F + kb + lg * 8);
    }
    short8 bfr[4];
#pragma unroll
    for (int fj = 0; fj < 4; ++fj) {
      int rk = fj * 16 + lr;
      short8 bv;
#pragma unroll
      for (int j = 0; j < 8; ++j)
        bv[j] = (short)f2bf(V[(size_t)(kb + lg * 8 + j) * RANK + rk]);
      bfr[fj] = bv;
    }
#pragma unroll
    for (int fi = 0; fi < 2; ++fi)
#pragma unroll
      for (int fj = 0; fj < 4; ++fj)
        acc[fi][fj] = __builtin_amdgcn_mfma_f32_16x16x32_bf16(af[fi], bfr[fj], acc[fi][fj], 0, 0, 0);
  }
  float a = act[0];
#pragma unroll
  for (int fi = 0; fi < 2; ++fi)
#pragma unroll
    for (int fj = 0; fj < 4; ++fj) {
      int rk = fj * 16 + lr;
      float sc = a * S[rk];
#pragma unroll
      for (int r = 0; r < 4; ++r) {
        int tok = mb + w * 32 + fi * 16 + lg * 4 + r;
        atomicAdd(t + tok * RANK + rk, acc[fi][fj][r] * sc);
      }
    }
}

// K3: out = bias + t @ U^T   (first writer of out)
__global__ __launch_bounds__(256) void k_lr2(const float* __restrict__ t,
                                             const float* __restrict__ U,
                                             const float* __restrict__ bias,
                                             float* __restrict__ out) {
  int bid = blockIdx.x;
  int mb = (bid & 3) * 128;
  int nb = (bid >> 2) * 128;
  int tid = threadIdx.x, w = tid >> 6, l = tid & 63;
  int lr = l & 15, lg = l >> 4;
  int wm = w >> 1, wn = w & 1;
  f32x4 acc[4][4] = {};
#pragma unroll
  for (int kk = 0; kk < 2; ++kk) {
    short8 af[4], bfr[4];
#pragma unroll
    for (int fi = 0; fi < 4; ++fi) {
      int row = mb + wm * 64 + fi * 16 + lr;
      const float4* tp = (const float4*)(t + (size_t)row * RANK + kk * 32 + lg * 8);
      float4 t0 = tp[0], t1 = tp[1];
      af[fi][0] = f2bf(t0.x); af[fi][1] = f2bf(t0.y);
      af[fi][2] = f2bf(t0.z); af[fi][3] = f2bf(t0.w);
      af[fi][4] = f2bf(t1.x); af[fi][5] = f2bf(t1.y);
      af[fi][6] = f2bf(t1.z); af[fi][7] = f2bf(t1.w);
    }
#pragma unroll
    for (int fj = 0; fj < 4; ++fj) {
      int row = nb + wn * 64 + fj * 16 + lr;
      const float4* up = (const float4*)(U + (size_t)row * RANK + kk * 32 + lg * 8);
      float4 u0 = up[0], u1 = up[1];
      bfr[fj][0] = f2bf(u0.x); bfr[fj][1] = f2bf(u0.y);
      bfr[fj][2] = f2bf(u0.z); bfr[fj][3] = f2bf(u0.w);
      bfr[fj][4] = f2bf(u1.x); bfr[fj][5] = f2bf(u1.y);
      bfr[fj][6] = f2bf(u1.z); bfr[fj][7] = f2bf(u1.w);
    }
#pragma unroll
    for (int fi = 0; fi < 4; ++fi)
#pragma unroll
      for (int fj = 0; fj < 4; ++fj)
        acc[fi][fj] = __builtin_amdgcn_mfma_f32_16x16x32_bf16(af[fi], bfr[fj], acc[fi][fj], 0, 0, 0);
  }
#pragma unroll
  for (int fj = 0; fj < 4; ++fj) {
    int o = nb + wn * 64 + fj * 16 + lr;
    float b = bias[o];
#pragma unroll
    for (int fi = 0; fi < 4; ++fi)
#pragma unroll
      for (int r = 0; r < 4; ++r) {
        int tok = mb + wm * 64 + fi * 16 + lg * 4 + r;
        out[(size_t)tok * OUT_F + o] = b + acc[fi][fj][r];
      }
  }
}

// K4: outliers + merge of 4 int32 GEMM partial slices
__global__ __launch_bounds__(256) void k_outlier_merge(
    const unsigned short* __restrict__ Abf, const int* __restrict__ rows,
    const int* __restrict__ cols, const float* __restrict__ vals,
    const float* __restrict__ act, const float* __restrict__ wscale,
    const int* __restrict__ part, float* __restrict__ out) {
  __shared__ float accr[OUT_F];
  int tk = blockIdx.x;
  for (int i = threadIdx.x; i < OUT_F; i += 256) accr[i] = 0.f;
  __syncthreads();
  float a = act[0];
  for (int i = threadIdx.x; i < NNZ; i += 256) {
    int r = rows[i], c = cols[i];
    float v = vals[i];
    float xq = bf2f(Abf[(size_t)tk * IN_F + c]);
    atomicAdd(accr + r, a * xq * v);
  }
  __syncthreads();
  float* orow = out + (size_t)tk * OUT_F;
  const int* p0 = part + (size_t)tk * OUT_F;
  const int* p1 = p0 + (size_t)TOKENS * OUT_F;
  const int* p2 = p1 + (size_t)TOKENS * OUT_F;
  const int* p3 = p2 + (size_t)TOKENS * OUT_F;
  for (int i = threadIdx.x * 4; i < OUT_F; i += 1024) {
    int4v s0 = *(const int4v*)(p0 + i);
    int4v s1 = *(const int4v*)(p1 + i);
    int4v s2 = *(const int4v*)(p2 + i);
    int4v s3 = *(const int4v*)(p3 + i);
    float4 ws = *(const float4*)(wscale + i);
    float4 ov = *(const float4*)(orow + i);
    ov.x += accr[i + 0] + (float)(s0[0] + s1[0] + s2[0] + s3[0]) * a * ws.x;
    ov.y += accr[i + 1] + (float)(s0[1] + s1[1] + s2[1] + s3[1]) * a * ws.y;
    ov.z += accr[i + 2] + (float)(s0[2] + s1[2] + s2[2] + s3[2]) * a * ws.z;
    ov.w += accr[i + 3] + (float)(s0[3] + s1[3] + s2[3] + s3[3]) * a * ws.w;
    *(float4*)(orow + i) = ov;
  }
}

// K5: part[ks] = x_q @ Wq[:,slice]^T; i8 MFMA; BM=512, BN=128, KSPLIT=4.
// 3-deep LDS ring: A staged 2 iters ahead (gload_lds), W regs 1 iter ahead,
// WAIT_VM(4) keeps next tile's 4 vmem ops in flight across each barrier.
__global__ __launch_bounds__(1024, 4) void k_gemm(const unsigned char* __restrict__ Aq,
                                                  const int* __restrict__ W,
                                                  int* __restrict__ part) {
  __shared__ __align__(16) unsigned char As[3][BM * BK];  // 96 KB
  __shared__ __align__(16) unsigned char Bs[3][BN * BK];  // 24 KB

  // XCD pair {2k,2k+1} owns ks=k (A-slice 1MB L2-resident per XCD pair)
  int d = blockIdx.x;
  int wg = (d & 7) * 32 + (d >> 3);   // 0..255
  int ks = wg >> 6;                   // 0..3
  int nb = wg & 63;                   // 0..63
  int kb0 = ks * KRANGE;

  int tid = threadIdx.x, w = tid >> 6, l = tid & 63;
  int lr = l & 15, lg = l >> 4;
  int wm = w >> 1, wn = w & 1;        // 8 wm x 2 wn; wave tile 64x64

  int4v acc[4][4] = {};
  int4v wa[2], wb[2];

  const int rW = tid >> 3;            // W row 0..127
  const int kcW = (tid & 7) * 8;      // int32 (=i8 byte) offset within BK
  const int uW = (kcW >> 4) ^ ((rW >> 1) & 3);
  const int offW = kcW & 15;

  auto LOAD_W = [&](int4v (&wr)[2], int kt) {
    const int* wp = W + (size_t)(nb * BN + rW) * IN_F + kb0 +
                    (kt & (NT - 1)) * BK + kcW;
    wr[0] = *(const int4v*)wp;
    wr[1] = *(const int4v*)(wp + 4);
  };
  // A i8 -> LDS direct; linear dest, pre-swizzled source (u ^= (r>>1)&3)
  auto STAGE_A = [&](int buf, int kt) {
    int kb = kb0 + (kt & (NT - 1)) * BK;
#pragma unroll
    for (int i = 0; i < 2; ++i) {
      int lidx = i * 1024 + w * 64;
      int U = lidx + l;
      int r = U >> 2, up = U & 3;
      int u = up ^ ((r >> 1) & 3);
      gload_lds16(Aq + (size_t)r * IN_F + kb + u * 16, &As[buf][(size_t)lidx * 16]);
    }
  };
  auto DSWRITE_B = [&](int buf, const int4v (&wr)[2]) {
    unsigned int w0 = 0, w1 = 0;
#pragma unroll
    for (int j = 0; j < 4; ++j) w0 |= ((unsigned)(wr[0][j] & 0xFF)) << (8 * j);
#pragma unroll
    for (int j = 0; j < 4; ++j) w1 |= ((unsigned)(wr[1][j] & 0xFF)) << (8 * j);
    uint2 val; val.x = w0; val.y = w1;
    *(uint2*)(&Bs[buf][(size_t)rW * BK + uW * 16 + offW]) = val;
  };
  auto LDFA = [&](int buf, int row) -> int4v {
    int u = lg ^ ((row >> 1) & 3);
    return *(const int4v*)(&As[buf][(size_t)row * BK + u * 16]);
  };
  auto LDFB = [&](int buf, int row) -> int4v {
    int u = lg ^ ((row >> 1) & 3);
    return *(const int4v*)(&Bs[buf][(size_t)row * BK + u * 16]);
  };
  auto COMPUTE = [&](int buf) {
    int4v b0 = LDFB(buf, wn * 64 + 0 * 16 + lr);
    int4v b1 = LDFB(buf, wn * 64 + 1 * 16 + lr);
    int4v b2 = LDFB(buf, wn * 64 + 2 * 16 + lr);
    int4v b3 = LDFB(buf, wn * 64 + 3 * 16 + lr);
    __builtin_amdgcn_s_setprio(1);
#pragma unroll
    for (int fi = 0; fi < 4; ++fi) {
      int4v af = LDFA(buf, wm * 64 + fi * 16 + lr);
      acc[fi][0] = __builtin_amdgcn_mfma_i32_16x16x64_i8(af, b0, acc[fi][0], 0, 0, 0);
      acc[fi][1] = __builtin_amdgcn_mfma_i32_16x16x64_i8(af, b1, acc[fi][1], 0, 0, 0);
      acc[fi][2] = __builtin_amdgcn_mfma_i32_16x16x64_i8(af, b2, acc[fi][2], 0, 0, 0);
      acc[fi][3] = __builtin_amdgcn_mfma_i32_16x16x64_i8(af, b3, acc[fi][3], 0, 0, 0);
    }
    __builtin_amdgcn_s_setprio(0);
  };

  // prologue: A0,W0,A1,W1 issued; retire A0+W0, write B0; A1,W1 stay in flight
  STAGE_A(0, 0);
  LOAD_W(wa, 0);
  STAGE_A(1, 1);
  LOAD_W(wb, 1);
  WAIT_VM(4);
  DSWRITE_B(0, wa);
  WAIT_LGKM0;
  SCHED0;
  __builtin_amdgcn_s_barrier();
  SCHED0;

  // steady: iter kt stages A(kt+2), loads W(kt+2); WAIT_VM(4) retires tile
  // kt+1's loads; ds-writes B(kt+1); barrier. Tile kt+2 stays in flight.
  int c = 0;  // buf of tile kt
  for (int kt = 0; kt < NT; kt += 2) {
    int c1 = c + 1 == 3 ? 0 : c + 1;
    int c2 = c1 + 1 == 3 ? 0 : c1 + 1;
    // even iter
    STAGE_A(c2, kt + 2);
    LOAD_W(wa, kt + 2);
    COMPUTE(c);
    WAIT_VM(4);
    DSWRITE_B(c1, wb);
    WAIT_LGKM0;
    SCHED0;
    __builtin_amdgcn_s_barrier();
    SCHED0;
    // odd iter
    STAGE_A(c, kt + 3);
    LOAD_W(wb, kt + 3);
    COMPUTE(c1);
    WAIT_VM(4);
    DSWRITE_B(c2, wa);
    WAIT_LGKM0;
    SCHED0;
    __builtin_amdgcn_s_barrier();
    SCHED0;
    c = c2;
  }

  // streaming i32 partial stores (unique writer per slice)
  int* pp = part + (size_t)ks * TOKENS * OUT_F;
#pragma unroll
  for (int fj = 0; fj < 4; ++fj) {
    int o = nb * BN + wn * 64 + fj * 16 + lr;
#pragma unroll
    for (int fi = 0; fi < 4; ++fi)
#pragma unroll
      for (int rr = 0; rr < 4; ++rr) {
        int tok = wm * 64 + fi * 16 + lg * 4 + rr;
        pp[(size_t)tok * OUT_F + o] = acc[fi][fj][rr];
      }
  }
}

extern "C" void kernel_launch(void* const* d_in, const int* in_sizes, int n_in,
                              void* d_out, int out_size, void* d_ws, size_t ws_size,
                              hipStream_t stream) {
  const float* x = (const float*)d_in[0];
  const int* W = (const int*)d_in[1];
  const float* wscale = (const float*)d_in[2];
  const float* smooth = (const float*)d_in[3];
  const float* act = (const float*)d_in[4];
  const int* orow = (const int*)d_in[5];
  const int* ocol = (const int*)d_in[6];
  const float* oval = (const float*)d_in[7];
  const float* U = (const float*)d_in[8];
  const float* S = (const float*)d_in[9];
  const float* V = (const float*)d_in[10];
  const float* bias = (const float*)d_in[11];
  float* out = (float*)d_out;

  unsigned short* Abf = (unsigned short*)d_ws;                           // 8 MB
  unsigned char* Aq = (unsigned char*)d_ws + (size_t)TOKENS * IN_F * 2;  // 4 MB
  float* t = (float*)((char*)d_ws + (size_t)TOKENS * IN_F * 3);          // 128 KB
  int* part = (int*)((char*)d_ws + (size_t)TOKENS * IN_F * 3 +
                     (size_t)TOKENS * RANK * 4);                         // 64 MB

  hipMemsetAsync(t, 0, TOKENS * RANK * sizeof(float), stream);
  k_quant<<<(TOKENS * IN_F / 4) / 256, 256, 0, stream>>>(x, smooth, act, Abf, Aq);
  k_gemm<<<256, 1024, 0, stream>>>(Aq, W, part);
  k_lr1<<<64, 256, 0, stream>>>(Abf, V, S, act, t);
  k_lr2<<<256, 256, 0, stream>>>(t, U, bias, out);
  k_outlier_merge<<<TOKENS, 256, 0, stream>>>(Abf, orow, ocol, oval, act,
                                              wscale, part, out);
}